// Round 1
// baseline (33118.604 us; speedup 1.0000x reference)
//
#include <hip/hip_runtime.h>
#include <hip/hip_bf16.h>

// ---------------------------------------------------------------------------
// LiveSR: classifier conv -> feature mean -> kmeans argmax routing ->
// per-sample EDSR expert (head, 8 resblocks, body+skip, 2x pixelshuffle x2, tail)
// Round 0: correctness-first fp32 direct convolution.
// ---------------------------------------------------------------------------

#define NSAMP 128
#define NSUB  10
#define NBLK  8
#define FCH   36

// ---------------- classifier: conv(3->512,3x3,SAME) + relu + mean ----------
__global__ __launch_bounds__(64)
void k_cls(const float* __restrict__ in, const float* __restrict__ w,
           const float* __restrict__ bias, float* __restrict__ feat)
{
    int n = blockIdx.x >> 9;      // /512
    int c = blockIdx.x & 511;
    int t = threadIdx.x;
    const float* wp = w + (size_t)c * 27;
    float wr[27];
#pragma unroll
    for (int i = 0; i < 27; ++i) wr[i] = wp[i];
    float bv = bias[c];
    const float* x = in + (size_t)n * 3072;
    float sum = 0.f;
    for (int p = t; p < 1024; p += 64) {
        int y = p >> 5, xx = p & 31;
        float acc = bv;
#pragma unroll
        for (int i = 0; i < 3; ++i) {
            const float* xi = x + i * 1024;
            const float* wi = wr + i * 9;
#pragma unroll
            for (int ky = 0; ky < 3; ++ky) {
                int yy = y + ky - 1;
                if ((unsigned)yy >= 32u) continue;
#pragma unroll
                for (int kx = 0; kx < 3; ++kx) {
                    int xc = xx + kx - 1;
                    if ((unsigned)xc >= 32u) continue;
                    acc += xi[yy * 32 + xc] * wi[ky * 3 + kx];
                }
            }
        }
        sum += fmaxf(acc, 0.f);
    }
#pragma unroll
    for (int off = 32; off; off >>= 1) sum += __shfl_down(sum, off);
    if (t == 0) feat[(size_t)n * 512 + c] = sum * (1.0f / 1024.0f);
}

// ---------------- kmeans scoring + argmax routing ---------------------------
__global__ __launch_bounds__(64)
void k_assign(const float* __restrict__ feat, const float* __restrict__ centers,
              int* __restrict__ assign)
{
    int n = blockIdx.x;
    int t = threadIdx.x;
    const float* f = feat + (size_t)n * 512;
    float best = -1e30f;
    int bi = 0;
    for (int k = 0; k < NSUB; ++k) {
        float s = 0.f;
        for (int d = t; d < 512; d += 64) {
            float df = f[d] - centers[(size_t)k * 512 + d];
            s += df * df;
        }
#pragma unroll
        for (int off = 32; off; off >>= 1) s += __shfl_down(s, off);
        if (t == 0) {
            float sc = 1.0f / s;
            if (sc > best) { best = sc; bi = k; }
        }
    }
    if (t == 0) assign[n] = bi;
}

// ---------------- head conv (3 -> 36 @32x32), writes h and b ----------------
__global__ __launch_bounds__(256)
void k_head(const float* __restrict__ in, const float* __restrict__ w,
            const float* __restrict__ bias, const int* __restrict__ assign,
            float* __restrict__ h, float* __restrict__ b, int base)
{
    int s = blockIdx.x / FCH, c = blockIdx.x - s * FCH;
    int n = base + s;
    int a = assign[n];
    const float* wp = w + (size_t)(a * FCH + c) * 27;
    float wr[27];
#pragma unroll
    for (int i = 0; i < 27; ++i) wr[i] = wp[i];
    float bv = bias[a * FCH + c];
    const float* x = in + (size_t)n * 3072;
    float* ho = h + ((size_t)s * FCH + c) * 1024;
    float* bo = b + ((size_t)s * FCH + c) * 1024;
    for (int p = threadIdx.x; p < 1024; p += 256) {
        int y = p >> 5, xx = p & 31;
        float acc = bv;
#pragma unroll
        for (int i = 0; i < 3; ++i) {
            const float* xi = x + i * 1024;
            const float* wi = wr + i * 9;
#pragma unroll
            for (int ky = 0; ky < 3; ++ky) {
                int yy = y + ky - 1;
                if ((unsigned)yy >= 32u) continue;
#pragma unroll
                for (int kx = 0; kx < 3; ++kx) {
                    int xc = xx + kx - 1;
                    if ((unsigned)xc >= 32u) continue;
                    acc += xi[yy * 32 + xc] * wi[ky * 3 + kx];
                }
            }
        }
        ho[p] = acc;
        bo[p] = acc;
    }
}

// ---------------- generic 36-in conv, templated on spatial size -------------
// SHUF: output has NC=144 channels, pixel-shuffled write to [36][2H][2H]
template<int H, bool RELU, bool SKIP, bool SHUF>
__global__ __launch_bounds__(256)
void k_conv(const float* __restrict__ in, const float* __restrict__ w,
            const float* __restrict__ bias, int w_estride, int w_sub,
            int b_estride, int b_sub, const int* __restrict__ assign,
            const float* __restrict__ skip, float* __restrict__ out,
            int base, int NC, int out_sstride)
{
    const int HH = H * H;
    int s = blockIdx.x / NC;
    int c = blockIdx.x - s * NC;
    int a = assign[base + s];
    const float* wp = w + (size_t)a * w_estride + w_sub + (size_t)c * 324;
    __shared__ float wl[324];
    for (int i = threadIdx.x; i < 324; i += 256) wl[i] = wp[i];
    float bv = bias[a * b_estride + b_sub + c];
    __syncthreads();

    const float* x = in + (size_t)s * FCH * HH;
    const float* sk = SKIP ? (skip + (size_t)s * FCH * HH + (size_t)c * HH) : nullptr;
    float* o;
    int dy = 0, dxo = 0;
    if (SHUF) {
        o = out + (size_t)s * out_sstride + (size_t)(c >> 2) * (4 * HH);
        dy = (c >> 1) & 1;
        dxo = c & 1;
    } else {
        o = out + (size_t)s * out_sstride + (size_t)c * HH;
    }

    for (int p = threadIdx.x; p < HH; p += 256) {
        int y = p / H, xx = p - y * H;
        float acc = bv;
        if (y > 0 && y < H - 1 && xx > 0 && xx < H - 1) {
            const float* xc = x + p - H - 1;
#pragma unroll 4
            for (int i = 0; i < FCH; ++i) {
                const float* xi = xc + i * HH;
                const float* wi = wl + i * 9;
                acc += xi[0] * wi[0] + xi[1] * wi[1] + xi[2] * wi[2];
                acc += xi[H] * wi[3] + xi[H + 1] * wi[4] + xi[H + 2] * wi[5];
                acc += xi[2 * H] * wi[6] + xi[2 * H + 1] * wi[7] + xi[2 * H + 2] * wi[8];
            }
        } else {
            for (int i = 0; i < FCH; ++i) {
                const float* xi = x + i * HH;
                const float* wi = wl + i * 9;
#pragma unroll
                for (int ky = 0; ky < 3; ++ky) {
                    int yy = y + ky - 1;
                    if ((unsigned)yy >= (unsigned)H) continue;
#pragma unroll
                    for (int kx = 0; kx < 3; ++kx) {
                        int xc2 = xx + kx - 1;
                        if ((unsigned)xc2 >= (unsigned)H) continue;
                        acc += xi[yy * H + xc2] * wi[ky * 3 + kx];
                    }
                }
            }
        }
        if (SKIP) acc += sk[p];
        if (RELU) acc = fmaxf(acc, 0.f);
        if (SHUF) o[(2 * y + dy) * (2 * H) + 2 * xx + dxo] = acc;
        else      o[p] = acc;
    }
}

// ---------------------------------------------------------------------------
extern "C" void kernel_launch(void* const* d_in, const int* in_sizes, int n_in,
                              void* d_out, int out_size, void* d_ws, size_t ws_size,
                              hipStream_t stream)
{
    const float* inputs  = (const float*)d_in[0];
    const float* cls_w   = (const float*)d_in[1];
    const float* cls_b   = (const float*)d_in[2];
    const float* centers = (const float*)d_in[3];
    const float* head_w  = (const float*)d_in[4];
    const float* head_b  = (const float*)d_in[5];
    const float* bw1     = (const float*)d_in[6];
    const float* bb1     = (const float*)d_in[7];
    const float* bw2     = (const float*)d_in[8];
    const float* bb2     = (const float*)d_in[9];
    const float* body_w  = (const float*)d_in[10];
    const float* body_b  = (const float*)d_in[11];
    const float* up1_w   = (const float*)d_in[12];
    const float* up1_b   = (const float*)d_in[13];
    const float* up2_w   = (const float*)d_in[14];
    const float* up2_b   = (const float*)d_in[15];
    const float* tail_w  = (const float*)d_in[16];
    const float* tail_b  = (const float*)d_in[17];
    float* out = (float*)d_out;

    float* ws = (float*)d_ws;
    float* feat = ws;                       // 128*512
    int*   assign = (int*)(ws + 65536);     // 128 ints (padded to 128 floats)
    float* chunk0 = ws + 65536 + 128;

    // per-sample chunk scratch (floats):
    //   h,b,t: 36*1024 each; U1: 36*4096; U2: 36*16384  => 847872 floats
    const size_t perS = 847872;
    int S = NSAMP;
    while (S > 1 && ((size_t)(65536 + 128) + (size_t)S * perS) * 4 > ws_size) S >>= 1;

    float* hB = chunk0;
    float* bB = hB + (size_t)S * 36864;
    float* tB = bB + (size_t)S * 36864;
    float* U1 = tB + (size_t)S * 36864;
    float* U2 = U1 + (size_t)S * 147456;

    // classifier + routing
    hipLaunchKernelGGL(k_cls, dim3(NSAMP * 512), dim3(64), 0, stream,
                       inputs, cls_w, cls_b, feat);
    hipLaunchKernelGGL(k_assign, dim3(NSAMP), dim3(64), 0, stream,
                       feat, centers, assign);

    for (int base = 0; base < NSAMP; base += S) {
        hipLaunchKernelGGL(k_head, dim3(S * FCH), dim3(256), 0, stream,
                           inputs, head_w, head_b, assign, hB, bB, base);
        for (int i = 0; i < NBLK; ++i) {
            // t = relu(conv(b))
            hipLaunchKernelGGL((k_conv<32, true, false, false>), dim3(S * FCH), dim3(256), 0, stream,
                               bB, bw1, bb1, 93312, i * 11664, NBLK * FCH, i * FCH,
                               assign, nullptr, tB, base, FCH, 36864);
            // b = b + conv(t)
            hipLaunchKernelGGL((k_conv<32, false, true, false>), dim3(S * FCH), dim3(256), 0, stream,
                               tB, bw2, bb2, 93312, i * 11664, NBLK * FCH, i * FCH,
                               assign, bB, bB, base, FCH, 36864);
        }
        // t = conv(b) + h   (global skip)
        hipLaunchKernelGGL((k_conv<32, false, true, false>), dim3(S * FCH), dim3(256), 0, stream,
                           bB, body_w, body_b, 11664, 0, FCH, 0,
                           assign, hB, tB, base, FCH, 36864);
        // up1: conv(36->144 @32x32) + pixelshuffle -> U1 [36,64,64]
        hipLaunchKernelGGL((k_conv<32, false, false, true>), dim3(S * 144), dim3(256), 0, stream,
                           tB, up1_w, up1_b, 46656, 0, 144, 0,
                           assign, nullptr, U1, base, 144, 147456);
        // up2: conv(36->144 @64x64) + pixelshuffle -> U2 [36,128,128]
        hipLaunchKernelGGL((k_conv<64, false, false, true>), dim3(S * 144), dim3(256), 0, stream,
                           U1, up2_w, up2_b, 46656, 0, 144, 0,
                           assign, nullptr, U2, base, 144, 589824);
        // tail: conv(36->3 @128x128) -> out
        hipLaunchKernelGGL((k_conv<128, false, false, false>), dim3(S * 3), dim3(256), 0, stream,
                           U2, tail_w, tail_b, 972, 0, 3, 0,
                           assign, nullptr, out + (size_t)base * 49152, base, 3, 49152);
    }
}

// Round 2
// 3647.923 us; speedup vs baseline: 9.0788x; 9.0788x over previous
//
#include <hip/hip_runtime.h>
#include <hip/hip_bf16.h>

// ---------------------------------------------------------------------------
// LiveSR round 1: register-blocked fp32 direct conv.
// Each thread: 8 contiguous pixels x COG output channels (48 accumulators),
// weights staged in LDS (broadcast reads), float4 input loads, fused
// pixel-shuffle / residual / relu epilogues.
// ---------------------------------------------------------------------------

#define NSAMP 128
#define NSUB  10
#define NBLK  8
#define FCH   36

// ---------------- kmeans scoring + argmax routing ---------------------------
__global__ __launch_bounds__(64)
void k_assign(const float* __restrict__ feat, const float* __restrict__ centers,
              int* __restrict__ assign)
{
    int n = blockIdx.x;
    int t = threadIdx.x;
    const float* f = feat + (size_t)n * 512;
    float best = -1e30f;
    int bi = 0;
    for (int k = 0; k < NSUB; ++k) {
        float s = 0.f;
        for (int d = t; d < 512; d += 64) {
            float df = f[d] - centers[(size_t)k * 512 + d];
            s += df * df;
        }
#pragma unroll
        for (int off = 32; off; off >>= 1) s += __shfl_down(s, off);
        if (t == 0) {
            float sc = 1.0f / s;
            if (sc > best) { best = sc; bi = k; }
        }
    }
    if (t == 0) assign[n] = bi;
}

// ---------------- classifier: conv(3->512) + relu + mean --------------------
// block = (sample, group of 8 out channels); 128 threads; thread = 8 px.
__global__ __launch_bounds__(128)
void k_cls2(const float* __restrict__ in, const float* __restrict__ w,
            const float* __restrict__ bias, float* __restrict__ feat)
{
    int bid = blockIdx.x;
    int n = bid >> 6;          // /64 groups
    int cg = bid & 63;
    __shared__ float wl[8 * 27];
    const float* wp = w + (size_t)(cg * 8) * 27;
    for (int i = threadIdx.x; i < 216; i += 128) wl[i] = wp[i];
    __syncthreads();

    int tx = threadIdx.x & 3;
    int y  = threadIdx.x >> 2;
    int x0 = tx * 8;
    const float* x = in + (size_t)n * 3072;

    float acc[8][8];
#pragma unroll
    for (int j = 0; j < 8; ++j) {
        float bv = bias[cg * 8 + j];
#pragma unroll
        for (int k = 0; k < 8; ++k) acc[j][k] = bv;
    }

#pragma unroll
    for (int ci = 0; ci < 3; ++ci) {
        const float* pl = x + ci * 1024;
        float r0[10], r1[10], r2[10];
        {
            const float4* v = (const float4*)(pl + y * 32 + x0);
            float4 a = v[0], b = v[1];
            r1[1]=a.x; r1[2]=a.y; r1[3]=a.z; r1[4]=a.w;
            r1[5]=b.x; r1[6]=b.y; r1[7]=b.z; r1[8]=b.w;
            r1[0] = (x0 > 0)  ? pl[y*32 + x0 - 1] : 0.f;
            r1[9] = (x0 < 24) ? pl[y*32 + x0 + 8] : 0.f;
        }
        if (y > 0) {
            const float* row = pl + (y-1) * 32;
            const float4* v = (const float4*)(row + x0);
            float4 a = v[0], b = v[1];
            r0[1]=a.x; r0[2]=a.y; r0[3]=a.z; r0[4]=a.w;
            r0[5]=b.x; r0[6]=b.y; r0[7]=b.z; r0[8]=b.w;
            r0[0] = (x0 > 0)  ? row[x0 - 1] : 0.f;
            r0[9] = (x0 < 24) ? row[x0 + 8] : 0.f;
        } else {
#pragma unroll
            for (int k = 0; k < 10; ++k) r0[k] = 0.f;
        }
        if (y < 31) {
            const float* row = pl + (y+1) * 32;
            const float4* v = (const float4*)(row + x0);
            float4 a = v[0], b = v[1];
            r2[1]=a.x; r2[2]=a.y; r2[3]=a.z; r2[4]=a.w;
            r2[5]=b.x; r2[6]=b.y; r2[7]=b.z; r2[8]=b.w;
            r2[0] = (x0 > 0)  ? row[x0 - 1] : 0.f;
            r2[9] = (x0 < 24) ? row[x0 + 8] : 0.f;
        } else {
#pragma unroll
            for (int k = 0; k < 10; ++k) r2[k] = 0.f;
        }
#pragma unroll
        for (int j = 0; j < 8; ++j) {
            const float* ww = &wl[(j * 3 + ci) * 9];
            float w0=ww[0],w1=ww[1],w2=ww[2],w3=ww[3],w4=ww[4],
                  w5=ww[5],w6=ww[6],w7=ww[7],w8=ww[8];
#pragma unroll
            for (int k = 0; k < 8; ++k)
                acc[j][k] += r0[k]*w0 + r0[k+1]*w1 + r0[k+2]*w2
                           + r1[k]*w3 + r1[k+1]*w4 + r1[k+2]*w5
                           + r2[k]*w6 + r2[k+1]*w7 + r2[k+2]*w8;
        }
    }

    // relu + per-thread partial sums, then block reduce (2 waves)
    float ps[8];
#pragma unroll
    for (int j = 0; j < 8; ++j) {
        float s = 0.f;
#pragma unroll
        for (int k = 0; k < 8; ++k) s += fmaxf(acc[j][k], 0.f);
        ps[j] = s;
    }
#pragma unroll
    for (int j = 0; j < 8; ++j) {
#pragma unroll
        for (int off = 32; off; off >>= 1) ps[j] += __shfl_down(ps[j], off);
    }
    __shared__ float red[2][8];
    int wv = threadIdx.x >> 6, ln = threadIdx.x & 63;
    if (ln == 0) {
#pragma unroll
        for (int j = 0; j < 8; ++j) red[wv][j] = ps[j];
    }
    __syncthreads();
    if (threadIdx.x < 8)
        feat[(size_t)n * 512 + cg * 8 + threadIdx.x] =
            (red[0][threadIdx.x] + red[1][threadIdx.x]) * (1.0f / 1024.0f);
}

// ---------------- generic register-blocked conv -----------------------------
// block: (sample, co-group of COG, row-block); 128 threads; thread = 8 px.
template<int H, int CIN, int COG, bool RELU, bool SKIP, bool SHUF, bool DUP>
__global__ __launch_bounds__(128)
void k_conv2(const float* __restrict__ in, const float* __restrict__ w,
             const float* __restrict__ bias, int w_estride, int w_sub,
             int b_estride, int b_sub, const int* __restrict__ assign,
             const float* __restrict__ skip, float* __restrict__ out,
             float* __restrict__ out2,
             int base, int NC, int in_sstride, int out_sstride)
{
    const int HH  = H * H;
    const int RB  = HH / 1024;          // row-blocks per image
    const int TPR = H / 8;              // threads per row
    const int G   = NC / COG;

    int bid = blockIdx.x;
    int s  = bid / (G * RB);
    int r  = bid - s * (G * RB);
    int g  = r / RB;
    int rb = r - g * RB;
    int a  = assign[base + s];

    __shared__ float wl[COG * CIN * 9];
    const float* wp = w + (size_t)a * w_estride + w_sub + (size_t)(g * COG) * CIN * 9;
    for (int i = threadIdx.x; i < COG * CIN * 9; i += 128) wl[i] = wp[i];
    __syncthreads();

    int tx = threadIdx.x % TPR;
    int ty = threadIdx.x / TPR;
    int y  = rb * (128 / TPR) + ty;
    int x0 = tx * 8;

    float acc[COG][8];
#pragma unroll
    for (int j = 0; j < COG; ++j) {
        float bv = bias[a * b_estride + b_sub + g * COG + j];
#pragma unroll
        for (int k = 0; k < 8; ++k) acc[j][k] = bv;
    }

    const float* x = in + (size_t)s * in_sstride;

    for (int ci = 0; ci < CIN; ++ci) {
        const float* pl = x + ci * HH;
        float r0[10], r1[10], r2[10];
        {
            const float* row = pl + y * H;
            const float4* v = (const float4*)(row + x0);
            float4 aa = v[0], bb = v[1];
            r1[1]=aa.x; r1[2]=aa.y; r1[3]=aa.z; r1[4]=aa.w;
            r1[5]=bb.x; r1[6]=bb.y; r1[7]=bb.z; r1[8]=bb.w;
            r1[0] = (x0 > 0)      ? row[x0 - 1] : 0.f;
            r1[9] = (x0 + 8 < H)  ? row[x0 + 8] : 0.f;
        }
        if (y > 0) {
            const float* row = pl + (y - 1) * H;
            const float4* v = (const float4*)(row + x0);
            float4 aa = v[0], bb = v[1];
            r0[1]=aa.x; r0[2]=aa.y; r0[3]=aa.z; r0[4]=aa.w;
            r0[5]=bb.x; r0[6]=bb.y; r0[7]=bb.z; r0[8]=bb.w;
            r0[0] = (x0 > 0)     ? row[x0 - 1] : 0.f;
            r0[9] = (x0 + 8 < H) ? row[x0 + 8] : 0.f;
        } else {
#pragma unroll
            for (int k = 0; k < 10; ++k) r0[k] = 0.f;
        }
        if (y < H - 1) {
            const float* row = pl + (y + 1) * H;
            const float4* v = (const float4*)(row + x0);
            float4 aa = v[0], bb = v[1];
            r2[1]=aa.x; r2[2]=aa.y; r2[3]=aa.z; r2[4]=aa.w;
            r2[5]=bb.x; r2[6]=bb.y; r2[7]=bb.z; r2[8]=bb.w;
            r2[0] = (x0 > 0)     ? row[x0 - 1] : 0.f;
            r2[9] = (x0 + 8 < H) ? row[x0 + 8] : 0.f;
        } else {
#pragma unroll
            for (int k = 0; k < 10; ++k) r2[k] = 0.f;
        }

#pragma unroll
        for (int j = 0; j < COG; ++j) {
            const float* ww = &wl[(j * CIN + ci) * 9];
            float w0=ww[0],w1=ww[1],w2=ww[2],w3=ww[3],w4=ww[4],
                  w5=ww[5],w6=ww[6],w7=ww[7],w8=ww[8];
#pragma unroll
            for (int k = 0; k < 8; ++k)
                acc[j][k] += r0[k]*w0 + r0[k+1]*w1 + r0[k+2]*w2
                           + r1[k]*w3 + r1[k+1]*w4 + r1[k+2]*w5
                           + r2[k]*w6 + r2[k+1]*w7 + r2[k+2]*w8;
        }
    }

    // epilogue
#pragma unroll
    for (int j = 0; j < COG; ++j) {
        int c = g * COG + j;
        if (SKIP) {
            const float* sp = skip + (size_t)s * out_sstride + (size_t)c * HH + y * H + x0;
            const float4* v = (const float4*)sp;
            float4 aa = v[0], bb = v[1];
            acc[j][0]+=aa.x; acc[j][1]+=aa.y; acc[j][2]+=aa.z; acc[j][3]+=aa.w;
            acc[j][4]+=bb.x; acc[j][5]+=bb.y; acc[j][6]+=bb.z; acc[j][7]+=bb.w;
        }
        if (RELU) {
#pragma unroll
            for (int k = 0; k < 8; ++k) acc[j][k] = fmaxf(acc[j][k], 0.f);
        }
        if (SHUF) {
            float* o = out + (size_t)s * out_sstride + (size_t)(c >> 2) * (4 * HH);
            int dy = (c >> 1) & 1, dx = c & 1;
            float* orow = o + (2 * y + dy) * (2 * H) + dx;
#pragma unroll
            for (int k = 0; k < 8; ++k) orow[2 * (x0 + k)] = acc[j][k];
        } else {
            float* o = out + (size_t)s * out_sstride + (size_t)c * HH + y * H + x0;
            float4 v0 = make_float4(acc[j][0], acc[j][1], acc[j][2], acc[j][3]);
            float4 v1 = make_float4(acc[j][4], acc[j][5], acc[j][6], acc[j][7]);
            ((float4*)o)[0] = v0;
            ((float4*)o)[1] = v1;
            if (DUP) {
                float* o2 = out2 + (size_t)s * out_sstride + (size_t)c * HH + y * H + x0;
                ((float4*)o2)[0] = v0;
                ((float4*)o2)[1] = v1;
            }
        }
    }
}

// ---------------------------------------------------------------------------
extern "C" void kernel_launch(void* const* d_in, const int* in_sizes, int n_in,
                              void* d_out, int out_size, void* d_ws, size_t ws_size,
                              hipStream_t stream)
{
    const float* inputs  = (const float*)d_in[0];
    const float* cls_w   = (const float*)d_in[1];
    const float* cls_b   = (const float*)d_in[2];
    const float* centers = (const float*)d_in[3];
    const float* head_w  = (const float*)d_in[4];
    const float* head_b  = (const float*)d_in[5];
    const float* bw1     = (const float*)d_in[6];
    const float* bb1     = (const float*)d_in[7];
    const float* bw2     = (const float*)d_in[8];
    const float* bb2     = (const float*)d_in[9];
    const float* body_w  = (const float*)d_in[10];
    const float* body_b  = (const float*)d_in[11];
    const float* up1_w   = (const float*)d_in[12];
    const float* up1_b   = (const float*)d_in[13];
    const float* up2_w   = (const float*)d_in[14];
    const float* up2_b   = (const float*)d_in[15];
    const float* tail_w  = (const float*)d_in[16];
    const float* tail_b  = (const float*)d_in[17];
    float* out = (float*)d_out;

    float* ws = (float*)d_ws;
    float* feat = ws;                       // 128*512
    int*   assign = (int*)(ws + 65536);     // 128 ints
    float* chunk0 = ws + 65536 + 128;

    // per-sample scratch (floats): h,b,t = 36864 each; U1 = 147456; U2 = 589824
    const size_t perS = 847872;
    int S = NSAMP;
    while (S > 1 && ((size_t)(65536 + 128) + (size_t)S * perS) * 4 > ws_size) S >>= 1;

    float* hB = chunk0;
    float* bB = hB + (size_t)S * 36864;
    float* tB = bB + (size_t)S * 36864;
    float* U1 = tB + (size_t)S * 36864;
    float* U2 = U1 + (size_t)S * 147456;

    // classifier + routing
    hipLaunchKernelGGL(k_cls2, dim3(NSAMP * 64), dim3(128), 0, stream,
                       inputs, cls_w, cls_b, feat);
    hipLaunchKernelGGL(k_assign, dim3(NSAMP), dim3(64), 0, stream,
                       feat, centers, assign);

    for (int base = 0; base < NSAMP; base += S) {
        // head: conv(3->36), write h and b
        hipLaunchKernelGGL((k_conv2<32, 3, 6, false, false, false, true>),
                           dim3(S * 6), dim3(128), 0, stream,
                           inputs + (size_t)base * 3072, head_w, head_b, 972, 0, 36, 0,
                           assign, nullptr, bB, hB, base, 36, 3072, 36864);
        for (int i = 0; i < NBLK; ++i) {
            // t = relu(conv(b))
            hipLaunchKernelGGL((k_conv2<32, 36, 6, true, false, false, false>),
                               dim3(S * 6), dim3(128), 0, stream,
                               bB, bw1, bb1, 93312, i * 11664, NBLK * FCH, i * FCH,
                               assign, nullptr, tB, nullptr, base, 36, 36864, 36864);
            // b = b + conv(t)
            hipLaunchKernelGGL((k_conv2<32, 36, 6, false, true, false, false>),
                               dim3(S * 6), dim3(128), 0, stream,
                               tB, bw2, bb2, 93312, i * 11664, NBLK * FCH, i * FCH,
                               assign, bB, bB, nullptr, base, 36, 36864, 36864);
        }
        // t = conv(b) + h   (global skip)
        hipLaunchKernelGGL((k_conv2<32, 36, 6, false, true, false, false>),
                           dim3(S * 6), dim3(128), 0, stream,
                           bB, body_w, body_b, 11664, 0, FCH, 0,
                           assign, hB, tB, nullptr, base, 36, 36864, 36864);
        // up1: conv(36->144 @32) + PS -> U1 [36,64,64]
        hipLaunchKernelGGL((k_conv2<32, 36, 6, false, false, true, false>),
                           dim3(S * 24), dim3(128), 0, stream,
                           tB, up1_w, up1_b, 46656, 0, 144, 0,
                           assign, nullptr, U1, nullptr, base, 144, 36864, 147456);
        // up2: conv(36->144 @64) + PS -> U2 [36,128,128]
        hipLaunchKernelGGL((k_conv2<64, 36, 6, false, false, true, false>),
                           dim3(S * 24 * 4), dim3(128), 0, stream,
                           U1, up2_w, up2_b, 46656, 0, 144, 0,
                           assign, nullptr, U2, nullptr, base, 144, 147456, 589824);
        // tail: conv(36->3 @128) -> out
        hipLaunchKernelGGL((k_conv2<128, 36, 3, false, false, false, false>),
                           dim3(S * 16), dim3(128), 0, stream,
                           U2, tail_w, tail_b, 972, 0, 3, 0,
                           assign, nullptr, out + (size_t)base * 49152, nullptr,
                           base, 3, 589824, 49152);
    }
}

// Round 3
// 1610.710 us; speedup vs baseline: 20.5615x; 2.2648x over previous
//
#include <hip/hip_runtime.h>
#include <hip/hip_bf16.h>

// ---------------------------------------------------------------------------
// LiveSR round 2: bf16 MFMA implicit-GEMM convolutions.
//  - channels-last padded activations [H+2][W+2][48] bf16 (halo + ch-pad = 0)
//  - conv = 9 accumulating GEMMs (one per tap), K = 64 (ch padded, zero wts)
//  - A (activations) from XOR-swizzled LDS tile, B (weights) from global regs
//  - pixel shuffle folded into weight regrouping (4 position-group convs)
//  - classifier/routing kept exact fp32
// ---------------------------------------------------------------------------

#define NSAMP 128
#define NSUB  10
#define NBLK  8

typedef __attribute__((ext_vector_type(8))) short bf16x8;
typedef __attribute__((ext_vector_type(4))) float f32x4;

__device__ inline short f2bf(float f) {
    union { float f; unsigned u; } v; v.f = f;
    unsigned r = (v.u + 0x7FFFu + ((v.u >> 16) & 1u)) >> 16;
    return (short)r;
}
__device__ inline float bf2f(short s) {
    union { unsigned u; float f; } v; v.u = ((unsigned)(unsigned short)s) << 16;
    return v.f;
}

// ---------------- weight / bias preprocessing -------------------------------
struct PrepDesc {
    const float* wsrc; const float* bsrc;
    int n_mat, CO_pad, CO_src, CO_real, CI_real, group;
    size_t sz_w, sz_b, wdst, bdst;   // sizes and dst offsets in elements
};
struct PrepTable { PrepDesc d[13]; };

__global__ __launch_bounds__(256)
void k_prep(PrepTable T, short* __restrict__ wb, float* __restrict__ bb,
            size_t wtot, size_t btot)
{
    size_t id = (size_t)blockIdx.x * 256 + threadIdx.x;
    if (id < wtot) {
        int s = 0; size_t off = id;
        while (off >= T.d[s].sz_w) { off -= T.d[s].sz_w; ++s; }
        const PrepDesc& D = T.d[s];
        int ci = (int)(off & 63);
        size_t q = off >> 6;
        int co = (int)(q % D.CO_pad);
        size_t q2 = q / D.CO_pad;
        int t = (int)(q2 % 9);
        int m = (int)(q2 / 9);
        float v = 0.f;
        if (co < D.CO_real && ci < D.CI_real) {
            int cs = (D.group >= 0) ? co * 4 + D.group : co;
            v = D.wsrc[(((size_t)m * D.CO_src + cs) * D.CI_real + ci) * 9 + t];
        }
        wb[D.wdst + off] = f2bf(v);
    } else if (id < wtot + btot) {
        size_t off = id - wtot;
        int s = 0;
        while (off >= T.d[s].sz_b) { off -= T.d[s].sz_b; ++s; }
        const PrepDesc& D = T.d[s];
        int co = (int)(off % D.CO_pad);
        int m  = (int)(off / D.CO_pad);
        float v = 0.f;
        if (co < D.CO_real) {
            int cs = (D.group >= 0) ? co * 4 + D.group : co;
            v = D.bsrc[(size_t)m * D.CO_src + cs];
        }
        bb[D.bdst + off] = v;
    }
}

__global__ __launch_bounds__(256)
void k_zero(uint4* __restrict__ p, long n)
{
    long stride = (long)gridDim.x * 256;
    for (long i = (long)blockIdx.x * 256 + threadIdx.x; i < n; i += stride)
        p[i] = make_uint4(0u, 0u, 0u, 0u);
}

// input fp32 NCHW [3][32][32] -> padded channels-last bf16 [34][34][48] ch0..2
__global__ __launch_bounds__(256)
void k_incl(const float* __restrict__ in, short* __restrict__ dst, int base, int S)
{
    int idx = blockIdx.x * 256 + threadIdx.x;
    if (idx >= S * 1024) return;
    int s = idx >> 10, p = idx & 1023;
    int y = p >> 5, x = p & 31;
    const float* src = in + (size_t)(base + s) * 3072 + p;
    short* d = dst + (((size_t)s * 34 + (y + 1)) * 34 + (x + 1)) * 48;
#pragma unroll
    for (int c = 0; c < 3; ++c) d[c] = f2bf(src[c * 1024]);
}

// ---------------- classifier (fp32, exact) ----------------------------------
__global__ __launch_bounds__(128)
void k_cls2(const float* __restrict__ in, const float* __restrict__ w,
            const float* __restrict__ bias, float* __restrict__ feat)
{
    int bid = blockIdx.x;
    int n = bid >> 6, cg = bid & 63;
    __shared__ float wl[8 * 27];
    const float* wp = w + (size_t)(cg * 8) * 27;
    for (int i = threadIdx.x; i < 216; i += 128) wl[i] = wp[i];
    __syncthreads();

    int tx = threadIdx.x & 3;
    int y  = threadIdx.x >> 2;
    int x0 = tx * 8;
    const float* x = in + (size_t)n * 3072;

    float acc[8][8];
#pragma unroll
    for (int j = 0; j < 8; ++j) {
        float bv = bias[cg * 8 + j];
#pragma unroll
        for (int k = 0; k < 8; ++k) acc[j][k] = bv;
    }

#pragma unroll
    for (int ci = 0; ci < 3; ++ci) {
        const float* pl = x + ci * 1024;
        float r0[10], r1[10], r2[10];
        {
            const float4* v = (const float4*)(pl + y * 32 + x0);
            float4 a = v[0], b = v[1];
            r1[1]=a.x; r1[2]=a.y; r1[3]=a.z; r1[4]=a.w;
            r1[5]=b.x; r1[6]=b.y; r1[7]=b.z; r1[8]=b.w;
            r1[0] = (x0 > 0)  ? pl[y*32 + x0 - 1] : 0.f;
            r1[9] = (x0 < 24) ? pl[y*32 + x0 + 8] : 0.f;
        }
        if (y > 0) {
            const float* row = pl + (y-1) * 32;
            const float4* v = (const float4*)(row + x0);
            float4 a = v[0], b = v[1];
            r0[1]=a.x; r0[2]=a.y; r0[3]=a.z; r0[4]=a.w;
            r0[5]=b.x; r0[6]=b.y; r0[7]=b.z; r0[8]=b.w;
            r0[0] = (x0 > 0)  ? row[x0 - 1] : 0.f;
            r0[9] = (x0 < 24) ? row[x0 + 8] : 0.f;
        } else {
#pragma unroll
            for (int k = 0; k < 10; ++k) r0[k] = 0.f;
        }
        if (y < 31) {
            const float* row = pl + (y+1) * 32;
            const float4* v = (const float4*)(row + x0);
            float4 a = v[0], b = v[1];
            r2[1]=a.x; r2[2]=a.y; r2[3]=a.z; r2[4]=a.w;
            r2[5]=b.x; r2[6]=b.y; r2[7]=b.z; r2[8]=b.w;
            r2[0] = (x0 > 0)  ? row[x0 - 1] : 0.f;
            r2[9] = (x0 < 24) ? row[x0 + 8] : 0.f;
        } else {
#pragma unroll
            for (int k = 0; k < 10; ++k) r2[k] = 0.f;
        }
#pragma unroll
        for (int j = 0; j < 8; ++j) {
            const float* ww = &wl[(j * 3 + ci) * 9];
            float w0=ww[0],w1=ww[1],w2=ww[2],w3=ww[3],w4=ww[4],
                  w5=ww[5],w6=ww[6],w7=ww[7],w8=ww[8];
#pragma unroll
            for (int k = 0; k < 8; ++k)
                acc[j][k] += r0[k]*w0 + r0[k+1]*w1 + r0[k+2]*w2
                           + r1[k]*w3 + r1[k+1]*w4 + r1[k+2]*w5
                           + r2[k]*w6 + r2[k+1]*w7 + r2[k+2]*w8;
        }
    }

    float ps[8];
#pragma unroll
    for (int j = 0; j < 8; ++j) {
        float s = 0.f;
#pragma unroll
        for (int k = 0; k < 8; ++k) s += fmaxf(acc[j][k], 0.f);
        ps[j] = s;
    }
#pragma unroll
    for (int j = 0; j < 8; ++j) {
#pragma unroll
        for (int off = 32; off; off >>= 1) ps[j] += __shfl_down(ps[j], off);
    }
    __shared__ float red[2][8];
    int wv = threadIdx.x >> 6, ln = threadIdx.x & 63;
    if (ln == 0) {
#pragma unroll
        for (int j = 0; j < 8; ++j) red[wv][j] = ps[j];
    }
    __syncthreads();
    if (threadIdx.x < 8)
        feat[(size_t)n * 512 + cg * 8 + threadIdx.x] =
            (red[0][threadIdx.x] + red[1][threadIdx.x]) * (1.0f / 1024.0f);
}

__global__ __launch_bounds__(64)
void k_assign(const float* __restrict__ feat, const float* __restrict__ centers,
              int* __restrict__ assign)
{
    int n = blockIdx.x;
    int t = threadIdx.x;
    const float* f = feat + (size_t)n * 512;
    float best = -1e30f;
    int bi = 0;
    for (int k = 0; k < NSUB; ++k) {
        float s = 0.f;
        for (int d = t; d < 512; d += 64) {
            float df = f[d] - centers[(size_t)k * 512 + d];
            s += df * df;
        }
#pragma unroll
        for (int off = 32; off; off >>= 1) s += __shfl_down(s, off);
        if (t == 0) {
            float sc = 1.0f / s;
            if (sc > best) { best = sc; bi = k; }
        }
    }
    if (t == 0) assign[n] = bi;
}

// ---------------- MFMA conv -------------------------------------------------
// EPI: 0 = store, 1 = store + skip-add, 2 = store to 2 bufs (head),
//      3 = decimated store (pixel-shuffle group g2), 4 = tail -> fp32 NCHW
template<int W, int NFRAG, int EPI, bool RELU>
__global__ __launch_bounds__(256)
void k_mconv(const short* __restrict__ act, size_t act_ss,
             const short* __restrict__ wt, size_t wt_es, int CO_pad,
             const float* __restrict__ bias, size_t b_es,
             const int* __restrict__ assign, int abase,
             short* __restrict__ out, size_t out_ss,
             const short* __restrict__ skip, size_t skip_ss,
             short* __restrict__ out2,
             float* __restrict__ fout,
             int g2)
{
    constexpr int MROWS = 128 / W;
    constexpr int PW = W + 2;
    constexpr int RB = (W * W) / 128;
    constexpr int LROWS = MROWS + 2;

    int bid = blockIdx.x;
    int s  = bid / RB;
    int rb = bid & (RB - 1);
    int a  = assign[abase + s];
    const short* wte = wt + (size_t)a * wt_es;
    const float* be  = bias + (size_t)a * b_es;

    __shared__ char lds[LROWS * PW * 128 + (EPI == 4 ? 1536 : 0)];

    // ---- stage activation tile: rows rb*MROWS .. +LROWS-1 of padded buffer
    {
        const short* src = act + (size_t)s * act_ss + (size_t)rb * MROWS * PW * 48;
        constexpr int NCH = LROWS * PW * 8;
        for (int i = threadIdx.x; i < NCH; i += 256) {
            int c  = i & 7;
            int pl = i >> 3;
            int px = pl % PW;
            uint4 v = make_uint4(0u, 0u, 0u, 0u);
            if (c < 6) v = *(const uint4*)(src + (size_t)pl * 48 + c * 8);
            *(uint4*)(&lds[pl * 128 + ((c * 16) ^ ((px & 7) << 4))]) = v;
        }
    }
    __syncthreads();

    int lane = threadIdx.x & 63;
    int wv   = threadIdx.x >> 6;
    int lm = lane & 15, lk = lane >> 4;

    f32x4 acc[2][NFRAG];
#pragma unroll
    for (int nf = 0; nf < NFRAG; ++nf) {
        float bb = be[nf * 16 + lm];
        f32x4 iv = { bb, bb, bb, bb };
        acc[0][nf] = iv;
        acc[1][nf] = iv;
    }

    int rA[2], xA[2];
#pragma unroll
    for (int q = 0; q < 2; ++q) {
        int pl = (wv * 2 + q) * 16 + lm;
        rA[q] = pl / W;
        xA[q] = pl % W;
    }

    // B double-buffer across taps
    bf16x8 Bc[NFRAG][2], Bn[NFRAG][2];
#pragma unroll
    for (int nf = 0; nf < NFRAG; ++nf) {
#pragma unroll
        for (int st = 0; st < 2; ++st)
            Bc[nf][st] = *(const bf16x8*)(wte + (size_t)(nf * 16 + lm) * 64 + st * 32 + lk * 8);
    }

#pragma unroll 1
    for (int t = 0; t < 9; ++t) {
        if (t < 8) {
#pragma unroll
            for (int nf = 0; nf < NFRAG; ++nf) {
#pragma unroll
                for (int st = 0; st < 2; ++st)
                    Bn[nf][st] = *(const bf16x8*)(wte + (size_t)((t + 1) * CO_pad + nf * 16 + lm) * 64 + st * 32 + lk * 8);
            }
        }
        int dy = t / 3 - 1, dx = t % 3 - 1;
#pragma unroll
        for (int q = 0; q < 2; ++q) {
            int ppx  = xA[q] + 1 + dx;
            int lrow = rA[q] + 1 + dy;
            int bofs = (lrow * PW + ppx) * 128;
            int sw   = (ppx & 7) << 4;
            bf16x8 A0 = *(const bf16x8*)(&lds[bofs + ((lk * 16) ^ sw)]);
            bf16x8 A1 = *(const bf16x8*)(&lds[bofs + (((lk + 4) * 16) ^ sw)]);
#pragma unroll
            for (int nf = 0; nf < NFRAG; ++nf) {
                acc[q][nf] = __builtin_amdgcn_mfma_f32_16x16x32_bf16(A0, Bc[nf][0], acc[q][nf], 0, 0, 0);
                acc[q][nf] = __builtin_amdgcn_mfma_f32_16x16x32_bf16(A1, Bc[nf][1], acc[q][nf], 0, 0, 0);
            }
        }
#pragma unroll
        for (int nf = 0; nf < NFRAG; ++nf) {
            Bc[nf][0] = Bn[nf][0];
            Bc[nf][1] = Bn[nf][1];
        }
    }

    // ---- epilogue
    if (EPI <= 3) {
#pragma unroll
        for (int q = 0; q < 2; ++q) {
#pragma unroll
            for (int rg = 0; rg < 4; ++rg) {
                int pe = (wv * 2 + q) * 16 + lk * 4 + rg;
                int rr = pe / W, xx = pe % W;
                int imr = rb * MROWS + rr;
#pragma unroll
                for (int nf = 0; nf < NFRAG; ++nf) {
                    int co = nf * 16 + lm;
                    float v = acc[q][nf][rg];
                    if (EPI == 1)
                        v += bf2f(skip[(size_t)s * skip_ss + ((size_t)(imr + 1) * PW + (xx + 1)) * 48 + co]);
                    if (RELU) v = fmaxf(v, 0.f);
                    short h = f2bf(v);
                    if (EPI == 3) {
                        int orow = 2 * imr + (g2 >> 1), ocol = 2 * xx + (g2 & 1);
                        out[(size_t)s * out_ss + ((size_t)(orow + 1) * (2 * W + 2) + (ocol + 1)) * 48 + co] = h;
                    } else {
                        size_t o = (size_t)s * out_ss + ((size_t)(imr + 1) * PW + (xx + 1)) * 48 + co;
                        out[o] = h;
                        if (EPI == 2) out2[o] = h;
                    }
                }
            }
        }
    } else {
        // tail: W=128, NFRAG=1, MROWS=1 -> one image row per block
        float* lo = (float*)&lds[LROWS * PW * 128];
        if (lm < 3) {
#pragma unroll
            for (int q = 0; q < 2; ++q)
#pragma unroll
                for (int rg = 0; rg < 4; ++rg) {
                    int pe = (wv * 2 + q) * 16 + lk * 4 + rg;
                    lo[lm * 128 + pe] = acc[q][0][rg];
                }
        }
        __syncthreads();
        if (threadIdx.x < 128) {
#pragma unroll
            for (int c = 0; c < 3; ++c)
                fout[((size_t)s * 3 + c) * 16384 + rb * 128 + threadIdx.x] = lo[c * 128 + threadIdx.x];
        }
    }
}

// ---------------------------------------------------------------------------
extern "C" void kernel_launch(void* const* d_in, const int* in_sizes, int n_in,
                              void* d_out, int out_size, void* d_ws, size_t ws_size,
                              hipStream_t stream)
{
    const float* inputs  = (const float*)d_in[0];
    const float* cls_w   = (const float*)d_in[1];
    const float* cls_b   = (const float*)d_in[2];
    const float* centers = (const float*)d_in[3];
    const float* head_w  = (const float*)d_in[4];
    const float* head_b  = (const float*)d_in[5];
    const float* bw1     = (const float*)d_in[6];
    const float* bb1     = (const float*)d_in[7];
    const float* bw2     = (const float*)d_in[8];
    const float* bb2     = (const float*)d_in[9];
    const float* body_w  = (const float*)d_in[10];
    const float* body_b  = (const float*)d_in[11];
    const float* up1_w   = (const float*)d_in[12];
    const float* up1_b   = (const float*)d_in[13];
    const float* up2_w   = (const float*)d_in[14];
    const float* up2_b   = (const float*)d_in[15];
    const float* tail_w  = (const float*)d_in[16];
    const float* tail_b  = (const float*)d_in[17];
    float* out = (float*)d_out;

    char* base = (char*)d_ws;
    size_t o = 0;
    auto A = [&](size_t bytes) { size_t r = o; o = (o + bytes + 255) & ~(size_t)255; return r; };

    size_t feat_o  = A(128 * 512 * 4);
    size_t asg_o   = A(512);

    const size_t HEAD_W = (size_t)10 * 9 * 48 * 64;   // elements
    const size_t BW_W   = (size_t)80 * 9 * 48 * 64;
    const size_t BODY_W = (size_t)10 * 9 * 48 * 64;
    const size_t UP_W   = (size_t)10 * 9 * 48 * 64;   // per group
    const size_t TAIL_W = (size_t)10 * 9 * 16 * 64;

    size_t headw_o = A(HEAD_W * 2);
    size_t bw1_o   = A(BW_W * 2);
    size_t bw2_o   = A(BW_W * 2);
    size_t bodyw_o = A(BODY_W * 2);
    size_t up1w_o  = A(4 * UP_W * 2);
    size_t up2w_o  = A(4 * UP_W * 2);
    size_t tailw_o = A(TAIL_W * 2);

    size_t headb_o = A(10 * 48 * 4);
    size_t bw1b_o  = A(80 * 48 * 4);
    size_t bw2b_o  = A(80 * 48 * 4);
    size_t bodyb_o = A(10 * 48 * 4);
    size_t up1b_o  = A(4 * 10 * 48 * 4);
    size_t up2b_o  = A(4 * 10 * 48 * 4);
    size_t tailb_o = A(10 * 16 * 4);

    size_t fixed_end = o;

    const size_t P32 = (size_t)34 * 34 * 48;
    const size_t PU1 = (size_t)66 * 66 * 48;
    const size_t PU2 = (size_t)130 * 130 * 48;
    const size_t perS = (4 * P32 + PU1 + PU2) * 2;    // bytes per sample

    int S = NSAMP;
    while (S > 1 && fixed_end + (size_t)S * perS > ws_size) S >>= 1;

    size_t act_o = o;
    short* inclB = (short*)(base + act_o);
    short* bB = inclB + (size_t)S * P32;
    short* tB = bB + (size_t)S * P32;
    short* hB = tB + (size_t)S * P32;
    short* U1 = hB + (size_t)S * P32;
    short* U2 = U1 + (size_t)S * PU1;

    float* feat   = (float*)(base + feat_o);
    int*   assign = (int*)(base + asg_o);
    short* wbase  = (short*)(base + headw_o);
    float* bbase  = (float*)(base + headb_o);

    short* headwt = (short*)(base + headw_o);
    short* bw1wt  = (short*)(base + bw1_o);
    short* bw2wt  = (short*)(base + bw2_o);
    short* bodywt = (short*)(base + bodyw_o);
    short* up1wt  = (short*)(base + up1w_o);
    short* up2wt  = (short*)(base + up2w_o);
    short* tailwt = (short*)(base + tailw_o);
    float* headbb = (float*)(base + headb_o);
    float* bw1bb  = (float*)(base + bw1b_o);
    float* bw2bb  = (float*)(base + bw2b_o);
    float* bodybb = (float*)(base + bodyb_o);
    float* up1bb  = (float*)(base + up1b_o);
    float* up2bb  = (float*)(base + up2b_o);
    float* tailbb = (float*)(base + tailb_o);

    // ---- build prep table
    PrepTable T;
    auto setd = [&](int i, const float* ws_, const float* bs_, int nm, int cop,
                    int cosrc, int coreal, int cireal, int grp,
                    size_t wdo, size_t bdo) {
        T.d[i].wsrc = ws_; T.d[i].bsrc = bs_;
        T.d[i].n_mat = nm; T.d[i].CO_pad = cop; T.d[i].CO_src = cosrc;
        T.d[i].CO_real = coreal; T.d[i].CI_real = cireal; T.d[i].group = grp;
        T.d[i].sz_w = (size_t)nm * 9 * cop * 64;
        T.d[i].sz_b = (size_t)nm * cop;
        T.d[i].wdst = (wdo - headw_o) / 2;
        T.d[i].bdst = (bdo - headb_o) / 4;
    };
    setd(0,  head_w, head_b, 10, 48, 36, 36, 3,  -1, headw_o, headb_o);
    setd(1,  bw1,    bb1,    80, 48, 36, 36, 36, -1, bw1_o,   bw1b_o);
    setd(2,  bw2,    bb2,    80, 48, 36, 36, 36, -1, bw2_o,   bw2b_o);
    setd(3,  body_w, body_b, 10, 48, 36, 36, 36, -1, bodyw_o, bodyb_o);
    for (int g = 0; g < 4; ++g)
        setd(4 + g, up1_w, up1_b, 10, 48, 144, 36, 36, g,
             up1w_o + (size_t)g * UP_W * 2, up1b_o + (size_t)g * 480 * 4);
    for (int g = 0; g < 4; ++g)
        setd(8 + g, up2_w, up2_b, 10, 48, 144, 36, 36, g,
             up2w_o + (size_t)g * UP_W * 2, up2b_o + (size_t)g * 480 * 4);
    setd(12, tail_w, tail_b, 10, 16, 3, 3, 36, -1, tailw_o, tailb_o);

    size_t wtot = 0, btot = 0;
    for (int i = 0; i < 13; ++i) { wtot += T.d[i].sz_w; btot += T.d[i].sz_b; }

    hipLaunchKernelGGL(k_prep, dim3((unsigned)((wtot + btot + 255) / 256)), dim3(256),
                       0, stream, T, wbase, bbase, wtot, btot);
    hipLaunchKernelGGL(k_zero, dim3(2048), dim3(256), 0, stream,
                       (uint4*)(base + act_o), (long)((size_t)S * perS / 16));
    hipLaunchKernelGGL(k_cls2, dim3(NSAMP * 64), dim3(128), 0, stream,
                       inputs, cls_w, cls_b, feat);
    hipLaunchKernelGGL(k_assign, dim3(NSAMP), dim3(64), 0, stream,
                       feat, centers, assign);

    const size_t WES_RES = (size_t)8 * 9 * 48 * 64;   // per-expert stride bw1/bw2
    const size_t WES_ONE = (size_t)9 * 48 * 64;       // per-expert stride single convs
    const size_t WES_TAIL = (size_t)9 * 16 * 64;

    for (int bs = 0; bs < NSAMP; bs += S) {
        hipLaunchKernelGGL(k_incl, dim3((S * 1024 + 255) / 256), dim3(256), 0, stream,
                           inputs, inclB, bs, S);
        // head: in_cl -> b and h
        hipLaunchKernelGGL((k_mconv<32, 3, 2, false>), dim3(S * 8), dim3(256), 0, stream,
                           inclB, P32, headwt, WES_ONE, 48, headbb, 48,
                           assign, bs, bB, P32, (const short*)nullptr, 0, hB,
                           (float*)nullptr, 0);
        for (int i = 0; i < NBLK; ++i) {
            hipLaunchKernelGGL((k_mconv<32, 3, 0, true>), dim3(S * 8), dim3(256), 0, stream,
                               bB, P32, bw1wt + (size_t)i * WES_ONE, WES_RES, 48,
                               bw1bb + i * 48, 8 * 48,
                               assign, bs, tB, P32, (const short*)nullptr, 0,
                               (short*)nullptr, (float*)nullptr, 0);
            hipLaunchKernelGGL((k_mconv<32, 3, 1, false>), dim3(S * 8), dim3(256), 0, stream,
                               tB, P32, bw2wt + (size_t)i * WES_ONE, WES_RES, 48,
                               bw2bb + i * 48, 8 * 48,
                               assign, bs, bB, P32, bB, P32,
                               (short*)nullptr, (float*)nullptr, 0);
        }
        // body: conv(b) + h -> t
        hipLaunchKernelGGL((k_mconv<32, 3, 1, false>), dim3(S * 8), dim3(256), 0, stream,
                           bB, P32, bodywt, WES_ONE, 48, bodybb, 48,
                           assign, bs, tB, P32, hB, P32,
                           (short*)nullptr, (float*)nullptr, 0);
        // up1: t -> U1 (4 shuffle-position groups)
        for (int g = 0; g < 4; ++g)
            hipLaunchKernelGGL((k_mconv<32, 3, 3, false>), dim3(S * 8), dim3(256), 0, stream,
                               tB, P32, up1wt + (size_t)g * UP_W, WES_ONE, 48,
                               up1bb + g * 480, 48,
                               assign, bs, U1, PU1, (const short*)nullptr, 0,
                               (short*)nullptr, (float*)nullptr, g);
        // up2: U1 -> U2
        for (int g = 0; g < 4; ++g)
            hipLaunchKernelGGL((k_mconv<64, 3, 3, false>), dim3(S * 32), dim3(256), 0, stream,
                               U1, PU1, up2wt + (size_t)g * UP_W, WES_ONE, 48,
                               up2bb + g * 480, 48,
                               assign, bs, U2, PU2, (const short*)nullptr, 0,
                               (short*)nullptr, (float*)nullptr, g);
        // tail: U2 -> out (fp32 NCHW)
        hipLaunchKernelGGL((k_mconv<128, 1, 4, false>), dim3(S * 128), dim3(256), 0, stream,
                           U2, PU2, tailwt, WES_TAIL, 16, tailbb, 16,
                           assign, bs, (short*)nullptr, 0, (const short*)nullptr, 0,
                           (short*)nullptr, out + (size_t)bs * 49152, 0);
    }
}

// Round 4
// 1246.457 us; speedup vs baseline: 26.5702x; 1.2922x over previous
//
#include <hip/hip_runtime.h>
#include <hip/hip_bf16.h>

// ---------------------------------------------------------------------------
// LiveSR round 3: bf16 MFMA implicit-GEMM + coalesced LDS-bounce epilogues.
//  - merged 4-group up-convs (wave = shuffle group), input staged once
//  - all stores via LDS bounce -> uint4 full-line writes (no write-allocate)
//  - tail re-tiled 2 rows x 64 cols (2x halo amp instead of 3x)
//  - halo-only zero init; XCD-aware bijective block swizzle (sample->XCD)
// ---------------------------------------------------------------------------

#define NSAMP 128
#define NSUB  10
#define NBLK  8

typedef __attribute__((ext_vector_type(8))) short bf16x8;
typedef __attribute__((ext_vector_type(4))) float f32x4;

__device__ inline short f2bf(float f) {
    union { float f; unsigned u; } v; v.f = f;
    unsigned r = (v.u + 0x7FFFu + ((v.u >> 16) & 1u)) >> 16;
    return (short)r;
}
__device__ inline float bf2f(short s) {
    union { unsigned u; float f; } v; v.u = ((unsigned)(unsigned short)s) << 16;
    return v.f;
}

union U16 { uint4 u; short s[8]; };

// sample->XCD-stable bijective swizzle (assumes XCD = dispatch_id % 8)
template<int RB>
__device__ inline void swz(int p, int S, int& s, int& rb) {
    if ((S & 7) == 0) {
        int x = p & 7, q = p >> 3;
        int sp = q / RB;
        s = x * (S >> 3) + sp;
        rb = q - sp * RB;
    } else {
        s = p / RB; rb = p - s * RB;
    }
}

// ---------------- weight / bias preprocessing -------------------------------
struct PrepDesc {
    const float* wsrc; const float* bsrc;
    int n_mat, CO_pad, CO_src, CO_real, CI_real, group;
    size_t sz_w, sz_b, wdst, bdst;
};
struct PrepTable { PrepDesc d[13]; };

__global__ __launch_bounds__(256)
void k_prep(PrepTable T, short* __restrict__ wb, float* __restrict__ bb,
            size_t wtot, size_t btot)
{
    size_t id = (size_t)blockIdx.x * 256 + threadIdx.x;
    if (id < wtot) {
        int s = 0; size_t off = id;
        while (off >= T.d[s].sz_w) { off -= T.d[s].sz_w; ++s; }
        const PrepDesc& D = T.d[s];
        int ci = (int)(off & 63);
        size_t q = off >> 6;
        int co = (int)(q % D.CO_pad);
        size_t q2 = q / D.CO_pad;
        int t = (int)(q2 % 9);
        int m = (int)(q2 / 9);
        float v = 0.f;
        if (co < D.CO_real && ci < D.CI_real) {
            int cs = (D.group >= 0) ? co * 4 + D.group : co;
            v = D.wsrc[(((size_t)m * D.CO_src + cs) * D.CI_real + ci) * 9 + t];
        }
        wb[D.wdst + off] = f2bf(v);
    } else if (id < wtot + btot) {
        size_t off = id - wtot;
        int s = 0;
        while (off >= T.d[s].sz_b) { off -= T.d[s].sz_b; ++s; }
        const PrepDesc& D = T.d[s];
        int co = (int)(off % D.CO_pad);
        int m  = (int)(off / D.CO_pad);
        float v = 0.f;
        if (co < D.CO_real) {
            int cs = (D.group >= 0) ? co * 4 + D.group : co;
            v = D.bsrc[(size_t)m * D.CO_src + cs];
        }
        bb[D.bdst + off] = v;
    }
}

// zero only the halo perimeter of a padded [Hp][Hp][48] bf16 buffer
__global__ __launch_bounds__(256)
void k_halo(short* __restrict__ p, int Hp, long sstride, int S)
{
    int perim = 4 * Hp - 4;
    long tot = (long)S * perim * 6;
    long u = (long)blockIdx.x * 256 + threadIdx.x;
    if (u >= tot) return;
    int k = (int)(u % 6);
    long q = u / 6;
    int e = (int)(q % perim);
    int s = (int)(q / perim);
    int r, c;
    if (e < Hp)            { r = 0;       c = e; }
    else if (e < 2 * Hp)   { r = Hp - 1;  c = e - Hp; }
    else { int e2 = e - 2 * Hp; r = 1 + (e2 >> 1); c = (e2 & 1) ? Hp - 1 : 0; }
    *(uint4*)(p + (long)s * sstride + ((long)r * Hp + c) * 48 + k * 8) =
        make_uint4(0u, 0u, 0u, 0u);
}

// input fp32 NCHW -> padded channels-last bf16 [34][34][48], full 48ch written
__global__ __launch_bounds__(256)
void k_incl(const float* __restrict__ in, short* __restrict__ dst, int base, int S)
{
    int idx = blockIdx.x * 256 + threadIdx.x;
    if (idx >= S * 1024) return;
    int s = idx >> 10, p = idx & 1023;
    int y = p >> 5, x = p & 31;
    const float* src = in + (size_t)(base + s) * 3072 + p;
    short* d = dst + (((long)s * 34 + (y + 1)) * 34 + (x + 1)) * 48;
    uint4 z = make_uint4(0u, 0u, 0u, 0u);
    U16 a; a.u = z;
    a.s[0] = f2bf(src[0]);
    a.s[1] = f2bf(src[1024]);
    a.s[2] = f2bf(src[2048]);
    ((uint4*)d)[0] = a.u;
#pragma unroll
    for (int k = 1; k < 6; ++k) ((uint4*)d)[k] = z;
}

// ---------------- classifier (fp32, exact) ----------------------------------
__global__ __launch_bounds__(128)
void k_cls2(const float* __restrict__ in, const float* __restrict__ w,
            const float* __restrict__ bias, float* __restrict__ feat)
{
    int bid = blockIdx.x;
    int n = bid >> 6, cg = bid & 63;
    __shared__ float wl[8 * 27];
    const float* wp = w + (size_t)(cg * 8) * 27;
    for (int i = threadIdx.x; i < 216; i += 128) wl[i] = wp[i];
    __syncthreads();

    int tx = threadIdx.x & 3;
    int y  = threadIdx.x >> 2;
    int x0 = tx * 8;
    const float* x = in + (size_t)n * 3072;

    float acc[8][8];
#pragma unroll
    for (int j = 0; j < 8; ++j) {
        float bv = bias[cg * 8 + j];
#pragma unroll
        for (int k = 0; k < 8; ++k) acc[j][k] = bv;
    }

#pragma unroll
    for (int ci = 0; ci < 3; ++ci) {
        const float* pl = x + ci * 1024;
        float r0[10], r1[10], r2[10];
        {
            const float4* v = (const float4*)(pl + y * 32 + x0);
            float4 a = v[0], b = v[1];
            r1[1]=a.x; r1[2]=a.y; r1[3]=a.z; r1[4]=a.w;
            r1[5]=b.x; r1[6]=b.y; r1[7]=b.z; r1[8]=b.w;
            r1[0] = (x0 > 0)  ? pl[y*32 + x0 - 1] : 0.f;
            r1[9] = (x0 < 24) ? pl[y*32 + x0 + 8] : 0.f;
        }
        if (y > 0) {
            const float* row = pl + (y-1) * 32;
            const float4* v = (const float4*)(row + x0);
            float4 a = v[0], b = v[1];
            r0[1]=a.x; r0[2]=a.y; r0[3]=a.z; r0[4]=a.w;
            r0[5]=b.x; r0[6]=b.y; r0[7]=b.z; r0[8]=b.w;
            r0[0] = (x0 > 0)  ? row[x0 - 1] : 0.f;
            r0[9] = (x0 < 24) ? row[x0 + 8] : 0.f;
        } else {
#pragma unroll
            for (int k = 0; k < 10; ++k) r0[k] = 0.f;
        }
        if (y < 31) {
            const float* row = pl + (y+1) * 32;
            const float4* v = (const float4*)(row + x0);
            float4 a = v[0], b = v[1];
            r2[1]=a.x; r2[2]=a.y; r2[3]=a.z; r2[4]=a.w;
            r2[5]=b.x; r2[6]=b.y; r2[7]=b.z; r2[8]=b.w;
            r2[0] = (x0 > 0)  ? row[x0 - 1] : 0.f;
            r2[9] = (x0 < 24) ? row[x0 + 8] : 0.f;
        } else {
#pragma unroll
            for (int k = 0; k < 10; ++k) r2[k] = 0.f;
        }
#pragma unroll
        for (int j = 0; j < 8; ++j) {
            const float* ww = &wl[(j * 3 + ci) * 9];
            float w0=ww[0],w1=ww[1],w2=ww[2],w3=ww[3],w4=ww[4],
                  w5=ww[5],w6=ww[6],w7=ww[7],w8=ww[8];
#pragma unroll
            for (int k = 0; k < 8; ++k)
                acc[j][k] += r0[k]*w0 + r0[k+1]*w1 + r0[k+2]*w2
                           + r1[k]*w3 + r1[k+1]*w4 + r1[k+2]*w5
                           + r2[k]*w6 + r2[k+1]*w7 + r2[k+2]*w8;
        }
    }

    float ps[8];
#pragma unroll
    for (int j = 0; j < 8; ++j) {
        float s = 0.f;
#pragma unroll
        for (int k = 0; k < 8; ++k) s += fmaxf(acc[j][k], 0.f);
        ps[j] = s;
    }
#pragma unroll
    for (int j = 0; j < 8; ++j) {
#pragma unroll
        for (int off = 32; off; off >>= 1) ps[j] += __shfl_down(ps[j], off);
    }
    __shared__ float red[2][8];
    int wv = threadIdx.x >> 6, ln = threadIdx.x & 63;
    if (ln == 0) {
#pragma unroll
        for (int j = 0; j < 8; ++j) red[wv][j] = ps[j];
    }
    __syncthreads();
    if (threadIdx.x < 8)
        feat[(size_t)n * 512 + cg * 8 + threadIdx.x] =
            (red[0][threadIdx.x] + red[1][threadIdx.x]) * (1.0f / 1024.0f);
}

__global__ __launch_bounds__(64)
void k_assign(const float* __restrict__ feat, const float* __restrict__ centers,
              int* __restrict__ assign)
{
    int n = blockIdx.x;
    int t = threadIdx.x;
    const float* f = feat + (size_t)n * 512;
    float best = -1e30f;
    int bi = 0;
    for (int k = 0; k < NSUB; ++k) {
        float s = 0.f;
        for (int d = t; d < 512; d += 64) {
            float df = f[d] - centers[(size_t)k * 512 + d];
            s += df * df;
        }
#pragma unroll
        for (int off = 32; off; off >>= 1) s += __shfl_down(s, off);
        if (t == 0) {
            float sc = 1.0f / s;
            if (sc > best) { best = sc; bi = k; }
        }
    }
    if (t == 0) assign[n] = bi;
}

// ---------------- residual-type conv (32x32, 48co) --------------------------
// EPI: 0 = store, 1 = store + skip-add (fp32), 2 = store to out and out2
template<int EPI, bool RELU>
__global__ __launch_bounds__(256)
void k_conv_res(const short* __restrict__ act, long act_ss,
                const short* __restrict__ wt, long wt_es,
                const float* __restrict__ bias, long b_es,
                const int* __restrict__ assign, int abase,
                short* __restrict__ out, long out_ss,
                const short* __restrict__ skip,
                short* __restrict__ out2, int S)
{
    constexpr int PW = 34, LROWS = 6, RB = 8;
    __shared__ __align__(16) char lds[LROWS * PW * 128 + 128 * 52 * 4];
    float* bounce = (float*)&lds[LROWS * PW * 128];

    int s, rb;
    swz<RB>(blockIdx.x, S, s, rb);
    int a = assign[abase + s];
    const short* wte = wt + (long)a * wt_es;
    const float* be  = bias + (long)a * b_es;

    {
        const short* src = act + (long)s * act_ss + (long)rb * 4 * PW * 48;
        constexpr int NCH = LROWS * PW * 8;
        for (int i = threadIdx.x; i < NCH; i += 256) {
            int c = i & 7, pl = i >> 3, px = pl % PW;
            uint4 v = make_uint4(0u, 0u, 0u, 0u);
            if (c < 6) v = *(const uint4*)(src + (long)pl * 48 + c * 8);
            *(uint4*)(&lds[pl * 128 + ((c * 16) ^ ((px & 7) << 4))]) = v;
        }
    }
    __syncthreads();

    int lane = threadIdx.x & 63, wv = threadIdx.x >> 6;
    int lm = lane & 15, lk = lane >> 4;

    f32x4 acc[2][3];
#pragma unroll
    for (int nf = 0; nf < 3; ++nf) {
        float bb = be[nf * 16 + lm];
        f32x4 iv = { bb, bb, bb, bb };
        acc[0][nf] = iv; acc[1][nf] = iv;
    }
    int rA[2], xA[2];
#pragma unroll
    for (int q = 0; q < 2; ++q) {
        int pl = (wv * 2 + q) * 16 + lm;
        rA[q] = pl >> 5; xA[q] = pl & 31;
    }

    bf16x8 Bc[3][2], Bn[3][2];
#pragma unroll
    for (int nf = 0; nf < 3; ++nf)
#pragma unroll
        for (int st = 0; st < 2; ++st)
            Bc[nf][st] = *(const bf16x8*)(wte + (long)(nf * 16 + lm) * 64 + st * 32 + lk * 8);

#pragma unroll 1
    for (int t = 0; t < 9; ++t) {
        if (t < 8) {
#pragma unroll
            for (int nf = 0; nf < 3; ++nf)
#pragma unroll
                for (int st = 0; st < 2; ++st)
                    Bn[nf][st] = *(const bf16x8*)(wte + (long)((t + 1) * 48 + nf * 16 + lm) * 64 + st * 32 + lk * 8);
        }
        int dy = t / 3 - 1, dx = t % 3 - 1;
#pragma unroll
        for (int q = 0; q < 2; ++q) {
            int ppx = xA[q] + 1 + dx;
            int bofs = ((rA[q] + 1 + dy) * PW + ppx) * 128;
            int sw = (ppx & 7) << 4;
            bf16x8 A0 = *(const bf16x8*)(&lds[bofs + ((lk * 16) ^ sw)]);
            bf16x8 A1 = *(const bf16x8*)(&lds[bofs + (((lk + 4) * 16) ^ sw)]);
#pragma unroll
            for (int nf = 0; nf < 3; ++nf) {
                acc[q][nf] = __builtin_amdgcn_mfma_f32_16x16x32_bf16(A0, Bc[nf][0], acc[q][nf], 0, 0, 0);
                acc[q][nf] = __builtin_amdgcn_mfma_f32_16x16x32_bf16(A1, Bc[nf][1], acc[q][nf], 0, 0, 0);
            }
        }
#pragma unroll
        for (int nf = 0; nf < 3; ++nf) {
            Bc[nf][0] = Bn[nf][0]; Bc[nf][1] = Bn[nf][1];
        }
    }

    // bounce (f32, px-line padded to 52 floats -> 2-way-max banks)
#pragma unroll
    for (int q = 0; q < 2; ++q)
#pragma unroll
        for (int nf = 0; nf < 3; ++nf)
#pragma unroll
            for (int rg = 0; rg < 4; ++rg) {
                int pe = (wv * 2 + q) * 16 + lk * 4 + rg;
                float v = acc[q][nf][rg];
                if (RELU) v = fmaxf(v, 0.f);
                bounce[pe * 52 + nf * 16 + lm] = v;
            }
    __syncthreads();

    for (int u = threadIdx.x; u < 768; u += 256) {
        int px = u / 6, k = u - px * 6;
        int r = px >> 5, x = px & 31;
        long off = (long)s * out_ss + ((long)(rb * 4 + r + 1) * PW + (x + 1)) * 48 + k * 8;
        f32x4 v0 = *(f32x4*)&bounce[px * 52 + k * 8];
        f32x4 v1 = *(f32x4*)&bounce[px * 52 + k * 8 + 4];
        if (EPI == 1) {
            U16 sk; sk.u = *(const uint4*)(skip + off);
            v0.x += bf2f(sk.s[0]); v0.y += bf2f(sk.s[1]);
            v0.z += bf2f(sk.s[2]); v0.w += bf2f(sk.s[3]);
            v1.x += bf2f(sk.s[4]); v1.y += bf2f(sk.s[5]);
            v1.z += bf2f(sk.s[6]); v1.w += bf2f(sk.s[7]);
        }
        U16 o;
        o.s[0] = f2bf(v0.x); o.s[1] = f2bf(v0.y); o.s[2] = f2bf(v0.z); o.s[3] = f2bf(v0.w);
        o.s[4] = f2bf(v1.x); o.s[5] = f2bf(v1.y); o.s[6] = f2bf(v1.z); o.s[7] = f2bf(v1.w);
        *(uint4*)(out + off) = o.u;
        if (EPI == 2) *(uint4*)(out2 + off) = o.u;
    }
}

// ---------------- merged 4-group up-conv (pixel shuffle fused) --------------
// wave w computes shuffle group w; all waves share the staged input tile.
template<int W, int INROWS>
__global__ __launch_bounds__(256)
void k_conv_up(const short* __restrict__ act, long act_ss,
               const short* __restrict__ wt, long grp_stride, long wt_es,
               const float* __restrict__ bias, long bgrp_stride, long b_es,
               const int* __restrict__ assign, int abase,
               short* __restrict__ out, long out_ss, int S)
{
    constexpr int PW = W + 2, LROWS = INROWS + 2, RB = W / INROWS;
    constexpr int OUTR = 2 * INROWS, OUTC = 2 * W, OPW = 2 * W + 2;
    constexpr int QF = INROWS * W / 16;
    __shared__ __align__(16) char lds[LROWS * PW * 128 + 6 * OUTR * OUTC * 16];
    short* bounce = (short*)&lds[LROWS * PW * 128];

    int s, rb;
    swz<RB>(blockIdx.x, S, s, rb);
    int a = assign[abase + s];
    int wv = threadIdx.x >> 6;
    const short* wte = wt + (long)wv * grp_stride + (long)a * wt_es;
    const float* be  = bias + (long)wv * bgrp_stride + (long)a * b_es;

    {
        const short* src = act + (long)s * act_ss + (long)rb * INROWS * PW * 48;
        constexpr int NCH = LROWS * PW * 8;
        for (int i = threadIdx.x; i < NCH; i += 256) {
            int c = i & 7, pl = i >> 3, px = pl % PW;
            uint4 v = make_uint4(0u, 0u, 0u, 0u);
            if (c < 6) v = *(const uint4*)(src + (long)pl * 48 + c * 8);
            *(uint4*)(&lds[pl * 128 + ((c * 16) ^ ((px & 7) << 4))]) = v;
        }
    }
    __syncthreads();

    int lane = threadIdx.x & 63;
    int lm = lane & 15, lk = lane >> 4;
    int dy = wv >> 1, dx2 = wv & 1;

    f32x4 acc[QF][3];
#pragma unroll
    for (int nf = 0; nf < 3; ++nf) {
        float bb = be[nf * 16 + lm];
        f32x4 iv = { bb, bb, bb, bb };
#pragma unroll
        for (int qf = 0; qf < QF; ++qf) acc[qf][nf] = iv;
    }
    int rA[QF], xA[QF];
#pragma unroll
    for (int qf = 0; qf < QF; ++qf) {
        int pl = qf * 16 + lm;
        rA[qf] = pl / W; xA[qf] = pl % W;
    }

    bf16x8 Bc[3][2], Bn[3][2];
#pragma unroll
    for (int nf = 0; nf < 3; ++nf)
#pragma unroll
        for (int st = 0; st < 2; ++st)
            Bc[nf][st] = *(const bf16x8*)(wte + (long)(nf * 16 + lm) * 64 + st * 32 + lk * 8);

#pragma unroll 1
    for (int t = 0; t < 9; ++t) {
        if (t < 8) {
#pragma unroll
            for (int nf = 0; nf < 3; ++nf)
#pragma unroll
                for (int st = 0; st < 2; ++st)
                    Bn[nf][st] = *(const bf16x8*)(wte + (long)((t + 1) * 48 + nf * 16 + lm) * 64 + st * 32 + lk * 8);
        }
        int tdy = t / 3 - 1, tdx = t % 3 - 1;
#pragma unroll
        for (int qf = 0; qf < QF; ++qf) {
            int ppx = xA[qf] + 1 + tdx;
            int bofs = ((rA[qf] + 1 + tdy) * PW + ppx) * 128;
            int sw = (ppx & 7) << 4;
            bf16x8 A0 = *(const bf16x8*)(&lds[bofs + ((lk * 16) ^ sw)]);
            bf16x8 A1 = *(const bf16x8*)(&lds[bofs + (((lk + 4) * 16) ^ sw)]);
#pragma unroll
            for (int nf = 0; nf < 3; ++nf) {
                acc[qf][nf] = __builtin_amdgcn_mfma_f32_16x16x32_bf16(A0, Bc[nf][0], acc[qf][nf], 0, 0, 0);
                acc[qf][nf] = __builtin_amdgcn_mfma_f32_16x16x32_bf16(A1, Bc[nf][1], acc[qf][nf], 0, 0, 0);
            }
        }
#pragma unroll
        for (int nf = 0; nf < 3; ++nf) {
            Bc[nf][0] = Bn[nf][0]; Bc[nf][1] = Bn[nf][1];
        }
    }

    // bounce layout: [6 k-planes][OUTR][OUTC][8 shorts] -> contiguous uint4 read
#pragma unroll
    for (int qf = 0; qf < QF; ++qf)
#pragma unroll
        for (int nf = 0; nf < 3; ++nf)
#pragma unroll
            for (int rg = 0; rg < 4; ++rg) {
                int pe = qf * 16 + lk * 4 + rg;
                int r = pe / W, x = pe % W;
                int plane = nf * 2 + (lm >> 3);
                int idx = (plane * OUTR * OUTC + (2 * r + dy) * OUTC + 2 * x + dx2) * 8 + (lm & 7);
                bounce[idx] = f2bf(acc[qf][nf][rg]);
            }
    __syncthreads();

    for (int u = threadIdx.x; u < 6 * OUTR * OUTC; u += 256) {
        int k = u / (OUTR * OUTC);
        int rem = u - k * (OUTR * OUTC);
        int rl = rem / OUTC, col = rem - rl * OUTC;
        long off = (long)s * out_ss + ((long)(rb * OUTR + rl + 1) * OPW + (col + 1)) * 48 + k * 8;
        *(uint4*)(out + off) = ((uint4*)bounce)[u];
    }
}

// ---------------- tail conv (36->3 @128x128) -> fp32 NCHW -------------------
__global__ __launch_bounds__(256)
void k_conv_tail(const short* __restrict__ act, long act_ss,
                 const short* __restrict__ wt, long wt_es,
                 const float* __restrict__ bias, long b_es,
                 const int* __restrict__ assign, int abase,
                 float* __restrict__ outp, int S)
{
    constexpr int PWS = 66, LROWS = 4, RB = 128;
    __shared__ __align__(16) char lds[LROWS * PWS * 128 + 3 * 2 * 64 * 4];
    float* bounce = (float*)&lds[LROWS * PWS * 128];

    int s, rb;
    swz<RB>(blockIdx.x, S, s, rb);
    int rowb = rb >> 1, colb = rb & 1;
    int a = assign[abase + s];
    const short* wte = wt + (long)a * wt_es;
    const float* be  = bias + (long)a * b_es;

    {
        constexpr int NCH = LROWS * PWS * 8;
        for (int i = threadIdx.x; i < NCH; i += 256) {
            int c = i & 7, pl = i >> 3;
            int lr = pl / PWS, lc = pl - lr * PWS;
            uint4 v = make_uint4(0u, 0u, 0u, 0u);
            if (c < 6)
                v = *(const uint4*)(act + (long)s * act_ss +
                        ((long)(rowb * 2 + lr) * 130 + colb * 64 + lc) * 48 + c * 8);
            *(uint4*)(&lds[pl * 128 + ((c * 16) ^ ((lc & 7) << 4))]) = v;
        }
    }
    __syncthreads();

    int lane = threadIdx.x & 63, wv = threadIdx.x >> 6;
    int lm = lane & 15, lk = lane >> 4;

    f32x4 acc[2];
    {
        float bb = be[lm];
        f32x4 iv = { bb, bb, bb, bb };
        acc[0] = iv; acc[1] = iv;
    }
    int rA[2], xA[2];
#pragma unroll
    for (int q = 0; q < 2; ++q) {
        int pl = (wv * 2 + q) * 16 + lm;
        rA[q] = pl >> 6; xA[q] = pl & 63;
    }

    bf16x8 Bc[2], Bn[2];
#pragma unroll
    for (int st = 0; st < 2; ++st)
        Bc[st] = *(const bf16x8*)(wte + (long)lm * 64 + st * 32 + lk * 8);

#pragma unroll 1
    for (int t = 0; t < 9; ++t) {
        if (t < 8) {
#pragma unroll
            for (int st = 0; st < 2; ++st)
                Bn[st] = *(const bf16x8*)(wte + (long)((t + 1) * 16 + lm) * 64 + st * 32 + lk * 8);
        }
        int dy = t / 3 - 1, dx = t % 3 - 1;
#pragma unroll
        for (int q = 0; q < 2; ++q) {
            int ppx = xA[q] + 1 + dx;
            int bofs = ((rA[q] + 1 + dy) * PWS + ppx) * 128;
            int sw = (ppx & 7) << 4;
            bf16x8 A0 = *(const bf16x8*)(&lds[bofs + ((lk * 16) ^ sw)]);
            bf16x8 A1 = *(const bf16x8*)(&lds[bofs + (((lk + 4) * 16) ^ sw)]);
            acc[q] = __builtin_amdgcn_mfma_f32_16x16x32_bf16(A0, Bc[0], acc[q], 0, 0, 0);
            acc[q] = __builtin_amdgcn_mfma_f32_16x16x32_bf16(A1, Bc[1], acc[q], 0, 0, 0);
        }
        Bc[0] = Bn[0]; Bc[1] = Bn[1];
    }

    if (lm < 3) {
#pragma unroll
        for (int q = 0; q < 2; ++q)
#pragma unroll
            for (int rg = 0; rg < 4; ++rg) {
                int pe = (wv * 2 + q) * 16 + lk * 4 + rg;
                int r = pe >> 6, x = pe & 63;
                bounce[(lm * 2 + r) * 64 + x] = acc[q][rg];
            }
    }
    __syncthreads();

    for (int u = threadIdx.x; u < 384; u += 256) {
        int c = u >> 7, r = (u >> 6) & 1, x = u & 63;
        outp[(long)s * 49152 + (long)c * 16384 + (long)(rowb * 2 + r) * 128 + colb * 64 + x] =
            bounce[(c * 2 + r) * 64 + x];
    }
}

// ---------------------------------------------------------------------------
extern "C" void kernel_launch(void* const* d_in, const int* in_sizes, int n_in,
                              void* d_out, int out_size, void* d_ws, size_t ws_size,
                              hipStream_t stream)
{
    const float* inputs  = (const float*)d_in[0];
    const float* cls_w   = (const float*)d_in[1];
    const float* cls_b   = (const float*)d_in[2];
    const float* centers = (const float*)d_in[3];
    const float* head_w  = (const float*)d_in[4];
    const float* head_b  = (const float*)d_in[5];
    const float* bw1     = (const float*)d_in[6];
    const float* bb1     = (const float*)d_in[7];
    const float* bw2     = (const float*)d_in[8];
    const float* bb2     = (const float*)d_in[9];
    const float* body_w  = (const float*)d_in[10];
    const float* body_b  = (const float*)d_in[11];
    const float* up1_w   = (const float*)d_in[12];
    const float* up1_b   = (const float*)d_in[13];
    const float* up2_w   = (const float*)d_in[14];
    const float* up2_b   = (const float*)d_in[15];
    const float* tail_w  = (const float*)d_in[16];
    const float* tail_b  = (const float*)d_in[17];
    float* out = (float*)d_out;

    char* base = (char*)d_ws;
    size_t o = 0;
    auto A = [&](size_t bytes) { size_t r = o; o = (o + bytes + 255) & ~(size_t)255; return r; };

    size_t feat_o  = A(128 * 512 * 4);
    size_t asg_o   = A(512);

    const size_t HEAD_W = (size_t)10 * 9 * 48 * 64;
    const size_t BW_W   = (size_t)80 * 9 * 48 * 64;
    const size_t BODY_W = (size_t)10 * 9 * 48 * 64;
    const size_t UP_W   = (size_t)10 * 9 * 48 * 64;   // per group
    const size_t TAIL_W = (size_t)10 * 9 * 16 * 64;

    size_t headw_o = A(HEAD_W * 2);
    size_t bw1_o   = A(BW_W * 2);
    size_t bw2_o   = A(BW_W * 2);
    size_t bodyw_o = A(BODY_W * 2);
    size_t up1w_o  = A(4 * UP_W * 2);
    size_t up2w_o  = A(4 * UP_W * 2);
    size_t tailw_o = A(TAIL_W * 2);

    size_t headb_o = A(10 * 48 * 4);
    size_t bw1b_o  = A(80 * 48 * 4);
    size_t bw2b_o  = A(80 * 48 * 4);
    size_t bodyb_o = A(10 * 48 * 4);
    size_t up1b_o  = A(4 * 10 * 48 * 4);
    size_t up2b_o  = A(4 * 10 * 48 * 4);
    size_t tailb_o = A(10 * 16 * 4);

    size_t fixed_end = o;

    const size_t P32 = (size_t)34 * 34 * 48;
    const size_t PU1 = (size_t)66 * 66 * 48;
    const size_t PU2 = (size_t)130 * 130 * 48;
    const size_t perS = (4 * P32 + PU1 + PU2) * 2;

    int S = NSAMP;
    while (S > 1 && fixed_end + (size_t)S * perS > ws_size) S >>= 1;

    short* inclB = (short*)(base + o);
    short* bB = inclB + (size_t)S * P32;
    short* tB = bB + (size_t)S * P32;
    short* hB = tB + (size_t)S * P32;
    short* U1 = hB + (size_t)S * P32;
    short* U2 = U1 + (size_t)S * PU1;

    float* feat   = (float*)(base + feat_o);
    int*   assign = (int*)(base + asg_o);
    short* wbase  = (short*)(base + headw_o);
    float* bbase  = (float*)(base + headb_o);

    short* headwt = (short*)(base + headw_o);
    short* bw1wt  = (short*)(base + bw1_o);
    short* bw2wt  = (short*)(base + bw2_o);
    short* bodywt = (short*)(base + bodyw_o);
    short* up1wt  = (short*)(base + up1w_o);
    short* up2wt  = (short*)(base + up2w_o);
    short* tailwt = (short*)(base + tailw_o);
    float* headbb = (float*)(base + headb_o);
    float* bw1bb  = (float*)(base + bw1b_o);
    float* bw2bb  = (float*)(base + bw2b_o);
    float* bodybb = (float*)(base + bodyb_o);
    float* up1bb  = (float*)(base + up1b_o);
    float* up2bb  = (float*)(base + up2b_o);
    float* tailbb = (float*)(base + tailb_o);

    PrepTable T;
    auto setd = [&](int i, const float* ws_, const float* bs_, int nm, int cop,
                    int cosrc, int coreal, int cireal, int grp,
                    size_t wdo, size_t bdo) {
        T.d[i].wsrc = ws_; T.d[i].bsrc = bs_;
        T.d[i].n_mat = nm; T.d[i].CO_pad = cop; T.d[i].CO_src = cosrc;
        T.d[i].CO_real = coreal; T.d[i].CI_real = cireal; T.d[i].group = grp;
        T.d[i].sz_w = (size_t)nm * 9 * cop * 64;
        T.d[i].sz_b = (size_t)nm * cop;
        T.d[i].wdst = (wdo - headw_o) / 2;
        T.d[i].bdst = (bdo - headb_o) / 4;
    };
    setd(0,  head_w, head_b, 10, 48, 36, 36, 3,  -1, headw_o, headb_o);
    setd(1,  bw1,    bb1,    80, 48, 36, 36, 36, -1, bw1_o,   bw1b_o);
    setd(2,  bw2,    bb2,    80, 48, 36, 36, 36, -1, bw2_o,   bw2b_o);
    setd(3,  body_w, body_b, 10, 48, 36, 36, 36, -1, bodyw_o, bodyb_o);
    for (int g = 0; g < 4; ++g)
        setd(4 + g, up1_w, up1_b, 10, 48, 144, 36, 36, g,
             up1w_o + (size_t)g * UP_W * 2, up1b_o + (size_t)g * 480 * 4);
    for (int g = 0; g < 4; ++g)
        setd(8 + g, up2_w, up2_b, 10, 48, 144, 36, 36, g,
             up2w_o + (size_t)g * UP_W * 2, up2b_o + (size_t)g * 480 * 4);
    setd(12, tail_w, tail_b, 10, 16, 3, 3, 36, -1, tailw_o, tailb_o);

    size_t wtot = 0, btot = 0;
    for (int i = 0; i < 13; ++i) { wtot += T.d[i].sz_w; btot += T.d[i].sz_b; }

    hipLaunchKernelGGL(k_prep, dim3((unsigned)((wtot + btot + 255) / 256)), dim3(256),
                       0, stream, T, wbase, bbase, wtot, btot);

    // halo-only zeroing (halos are never written by conv stores)
    auto halo = [&](short* p, int Hp, long ss) {
        long tot = (long)S * (4 * Hp - 4) * 6;
        hipLaunchKernelGGL(k_halo, dim3((unsigned)((tot + 255) / 256)), dim3(256),
                           0, stream, p, Hp, ss, S);
    };
    halo(inclB, 34, (long)P32);
    halo(bB,    34, (long)P32);
    halo(tB,    34, (long)P32);
    halo(U1,    66, (long)PU1);
    halo(U2,   130, (long)PU2);

    hipLaunchKernelGGL(k_cls2, dim3(NSAMP * 64), dim3(128), 0, stream,
                       inputs, cls_w, cls_b, feat);
    hipLaunchKernelGGL(k_assign, dim3(NSAMP), dim3(64), 0, stream,
                       feat, centers, assign);

    const long WES_RES  = 8L * 9 * 48 * 64;
    const long WES_ONE  = 9L * 9 * 48 * 64 / 9;   // 9*48*64
    const long WES_TAIL = 9L * 16 * 64;

    for (int bs = 0; bs < NSAMP; bs += S) {
        hipLaunchKernelGGL(k_incl, dim3((S * 1024 + 255) / 256), dim3(256), 0, stream,
                           inputs, inclB, bs, S);
        // head -> bB and hB
        hipLaunchKernelGGL((k_conv_res<2, false>), dim3(S * 8), dim3(256), 0, stream,
                           inclB, (long)P32, headwt, WES_ONE, headbb, 48L,
                           assign, bs, bB, (long)P32, (const short*)nullptr, hB, S);
        for (int i = 0; i < NBLK; ++i) {
            hipLaunchKernelGGL((k_conv_res<0, true>), dim3(S * 8), dim3(256), 0, stream,
                               bB, (long)P32, bw1wt + (size_t)i * WES_ONE, WES_RES,
                               bw1bb + i * 48, 8L * 48,
                               assign, bs, tB, (long)P32, (const short*)nullptr,
                               (short*)nullptr, S);
            hipLaunchKernelGGL((k_conv_res<1, false>), dim3(S * 8), dim3(256), 0, stream,
                               tB, (long)P32, bw2wt + (size_t)i * WES_ONE, WES_RES,
                               bw2bb + i * 48, 8L * 48,
                               assign, bs, bB, (long)P32, bB, (short*)nullptr, S);
        }
        // body + global skip -> tB
        hipLaunchKernelGGL((k_conv_res<1, false>), dim3(S * 8), dim3(256), 0, stream,
                           bB, (long)P32, bodywt, WES_ONE, bodybb, 48L,
                           assign, bs, tB, (long)P32, hB, (short*)nullptr, S);
        // up1 merged -> U1
        hipLaunchKernelGGL((k_conv_up<32, 2>), dim3(S * 16), dim3(256), 0, stream,
                           tB, (long)P32, up1wt, (long)UP_W, WES_ONE,
                           up1bb, 480L, 48L, assign, bs, U1, (long)PU1, S);
        // up2 merged -> U2
        hipLaunchKernelGGL((k_conv_up<64, 1>), dim3(S * 64), dim3(256), 0, stream,
                           U1, (long)PU1, up2wt, (long)UP_W, WES_ONE,
                           up2bb, 480L, 48L, assign, bs, U2, (long)PU2, S);
        // tail -> out fp32 NCHW
        hipLaunchKernelGGL(k_conv_tail, dim3(S * 128), dim3(256), 0, stream,
                           U2, (long)PU2, tailwt, WES_TAIL, tailbb, 16L,
                           assign, bs, out + (size_t)bs * 49152, S);
    }
}